// Round 2
// baseline (1072.594 us; speedup 1.0000x reference)
//
#include <hip/hip_runtime.h>

#define N_ROWS 262144
#define HID 512
#define HHALF 256
#define HEADS 8
#define GNUM 1024
#define LN_EPS 1e-5f

typedef __bf16 bf16x8 __attribute__((ext_vector_type(8)));
typedef float f32x4 __attribute__((ext_vector_type(4)));

// ---------------- zero graph_z + entropy ----------------
__global__ void k_zero(float4* __restrict__ gz, float* __restrict__ ent) {
    int t = blockIdx.x * 256 + threadIdx.x;
    gz[t] = make_float4(0.f, 0.f, 0.f, 0.f);
    if (t == 0) *ent = 0.f;
}

// ---------------- W1^T -> bf16 ----------------
__global__ void k_prep(const float* __restrict__ W1, __bf16* __restrict__ w1t) {
    int tid = blockIdx.x * 256 + threadIdx.x;
    int n = tid >> 9;   // output feature 0..255
    int k = tid & 511;  // input feature 0..511
    w1t[n * HID + k] = (__bf16)W1[k * HHALF + n];
}

// ---------------- segment starts (batch sorted) ----------------
__global__ void k_seg(const int* __restrict__ batch, int* __restrict__ seg) {
    int g = blockIdx.x * 256 + threadIdx.x;
    if (g > GNUM) return;
    int lo = 0, hi = N_ROWS;
    while (lo < hi) {
        int mid = (lo + hi) >> 1;
        if (batch[mid] < g) lo = mid + 1; else hi = mid;
    }
    seg[g] = lo;
}

// ---------------- fused LN(stats+apply) + GEMM 512->256 + silu + W2 -> logits ----------------
// 256 thr (4 waves); block tile 64 rows x 256 cols; wave tile 64 rows x 64 cols (waves split cols).
// A normalized->bf16 staged in LDS once per block; B staged per 64-wide K chunk. Stride 72 bf16.
__global__ __launch_bounds__(256) void k_gemm(
    const float* __restrict__ x, const float* __restrict__ gamma,
    const float* __restrict__ beta, const __bf16* __restrict__ w1t,
    const float* __restrict__ b1, const float* __restrict__ W2,
    const float* __restrict__ b2, float* __restrict__ logits)
{
    __shared__ __align__(16) __bf16 ldsb[256 * 72];   // 36864 B
    __shared__ __align__(16) __bf16 ldsa[64 * 72];    //  9216 B
    __shared__ float s_rstd[64], s_nmr[64];
    __shared__ float s_lp[4][64][8];                  //  8192 B

    const int tid = threadIdx.x;
    const int wid = tid >> 6, lane = tid & 63;
    const int q = lane >> 4, c = lane & 15;
    const int rowbase = blockIdx.x * 64;
    const float* xt = x + (size_t)rowbase * HID;
    const int r4 = tid >> 2, qt = tid & 3;   // 4 threads per row

    // ---- pass 1: LN stats (thread covers 128-float slice of its row)
    {
        const float4* xp = (const float4*)(xt + r4 * HID + qt * 128);
        float s = 0.f, qq = 0.f;
        #pragma unroll 8
        for (int i = 0; i < 32; ++i) {
            float4 v = xp[i];
            s += v.x + v.y + v.z + v.w;
            qq = fmaf(v.x, v.x, fmaf(v.y, v.y, fmaf(v.z, v.z, fmaf(v.w, v.w, qq))));
        }
        s += __shfl_xor(s, 1); qq += __shfl_xor(qq, 1);
        s += __shfl_xor(s, 2); qq += __shfl_xor(qq, 2);
        if (qt == 0) {
            float mu = s * (1.f / HID);
            float var = qq * (1.f / HID) - mu * mu;
            float rs = rsqrtf(var + LN_EPS);
            s_rstd[r4] = rs; s_nmr[r4] = -mu * rs;
        }
    }

    f32x4 acc[4][4];
    #pragma unroll
    for (int a = 0; a < 4; ++a)
        #pragma unroll
        for (int b = 0; b < 4; ++b) acc[a][b] = (f32x4)0.f;

    const int nrow = tid >> 3, segt = tid & 7;
    const int colbase = wid * 64;

    for (int ch = 0; ch < 8; ++ch) {
        const int k0 = ch * 64;
        __syncthreads();
        // B stage: 256 cols x 64 k
        #pragma unroll
        for (int it = 0; it < 8; ++it) {
            int n = nrow + it * 32;
            *(uint4*)(ldsb + n * 72 + segt * 8) =
                *(const uint4*)(w1t + n * HID + k0 + segt * 8);
        }
        // A stage: 64 rows x 64 k, LN apply + bf16 (x re-read hits L2/L3)
        {
            float rs = s_rstd[r4], nm = s_nmr[r4];
            const float4* xp = (const float4*)(xt + r4 * HID + k0 + qt * 16);
            const float4* gp = (const float4*)(gamma + k0 + qt * 16);
            const float4* bp = (const float4*)(beta + k0 + qt * 16);
            #pragma unroll
            for (int j = 0; j < 2; ++j) {
                float4 xa = xp[2 * j], xb = xp[2 * j + 1];
                float4 ga = gp[2 * j], gb = gp[2 * j + 1];
                float4 ba = bp[2 * j], bb = bp[2 * j + 1];
                bf16x8 o;
                o[0] = (__bf16)fmaf(fmaf(xa.x, rs, nm), ga.x, ba.x);
                o[1] = (__bf16)fmaf(fmaf(xa.y, rs, nm), ga.y, ba.y);
                o[2] = (__bf16)fmaf(fmaf(xa.z, rs, nm), ga.z, ba.z);
                o[3] = (__bf16)fmaf(fmaf(xa.w, rs, nm), ga.w, ba.w);
                o[4] = (__bf16)fmaf(fmaf(xb.x, rs, nm), gb.x, bb.x);
                o[5] = (__bf16)fmaf(fmaf(xb.y, rs, nm), gb.y, bb.y);
                o[6] = (__bf16)fmaf(fmaf(xb.z, rs, nm), gb.z, bb.z);
                o[7] = (__bf16)fmaf(fmaf(xb.w, rs, nm), gb.w, bb.w);
                *(bf16x8*)(ldsa + r4 * 72 + qt * 16 + j * 8) = o;
            }
        }
        __syncthreads();
        // compute: wave tile 64 rows x 64 cols
        bf16x8 bfr[4][2];
        #pragma unroll
        for (int cg = 0; cg < 4; ++cg) {
            int n = colbase + cg * 16 + c;
            bfr[cg][0] = *(const bf16x8*)(ldsb + n * 72 + q * 8);
            bfr[cg][1] = *(const bf16x8*)(ldsb + n * 72 + 32 + q * 8);
        }
        #pragma unroll
        for (int rg = 0; rg < 4; ++rg) {
            int m = rg * 16 + c;
            bf16x8 a0 = *(const bf16x8*)(ldsa + m * 72 + q * 8);
            bf16x8 a1 = *(const bf16x8*)(ldsa + m * 72 + 32 + q * 8);
            #pragma unroll
            for (int cg = 0; cg < 4; ++cg) {
                acc[rg][cg] = __builtin_amdgcn_mfma_f32_16x16x32_bf16(a0, bfr[cg][0], acc[rg][cg], 0, 0, 0);
                acc[rg][cg] = __builtin_amdgcn_mfma_f32_16x16x32_bf16(a1, bfr[cg][1], acc[rg][cg], 0, 0, 0);
            }
        }
    }

    // ---- epilogue: silu + W2 contraction; cols split across waves -> reduce via LDS
    #pragma unroll
    for (int rg = 0; rg < 4; ++rg) {
        float lp[4][8];
        #pragma unroll
        for (int r = 0; r < 4; ++r)
            #pragma unroll
            for (int hd = 0; hd < 8; ++hd) lp[r][hd] = 0.f;
        #pragma unroll
        for (int cg = 0; cg < 4; ++cg) {
            int n = colbase + cg * 16 + c;
            float b1v = b1[n];
            float4 w2a = *(const float4*)(W2 + n * 8);
            float4 w2b = *(const float4*)(W2 + n * 8 + 4);
            #pragma unroll
            for (int r = 0; r < 4; ++r) {
                float v = acc[rg][cg][r] + b1v;
                float h = v / (1.f + __expf(-v));
                lp[r][0] = fmaf(h, w2a.x, lp[r][0]);
                lp[r][1] = fmaf(h, w2a.y, lp[r][1]);
                lp[r][2] = fmaf(h, w2a.z, lp[r][2]);
                lp[r][3] = fmaf(h, w2a.w, lp[r][3]);
                lp[r][4] = fmaf(h, w2b.x, lp[r][4]);
                lp[r][5] = fmaf(h, w2b.y, lp[r][5]);
                lp[r][6] = fmaf(h, w2b.z, lp[r][6]);
                lp[r][7] = fmaf(h, w2b.w, lp[r][7]);
            }
        }
        #pragma unroll
        for (int m = 1; m < 16; m <<= 1)
            #pragma unroll
            for (int r = 0; r < 4; ++r)
                #pragma unroll
                for (int hd = 0; hd < 8; ++hd)
                    lp[r][hd] += __shfl_xor(lp[r][hd], m);
        if (c == 0) {
            #pragma unroll
            for (int r = 0; r < 4; ++r)
                #pragma unroll
                for (int hd = 0; hd < 8; ++hd)
                    s_lp[wid][rg * 16 + q * 4 + r][hd] = lp[r][hd];
        }
    }
    __syncthreads();
    #pragma unroll
    for (int idx = tid; idx < 512; idx += 256) {
        int row = idx >> 3, hd = idx & 7;
        float v = s_lp[0][row][hd] + s_lp[1][row][hd] + s_lp[2][row][hd]
                + s_lp[3][row][hd] + b2[hd];
        logits[(size_t)(rowbase + row) * 8 + hd] = v;
    }
}

// ---------------- per-graph softmax stats ----------------
__global__ __launch_bounds__(256) void k_gmax(
    const float* __restrict__ logits, const int* __restrict__ seg,
    float* __restrict__ smax8, float* __restrict__ sinv8)
{
    const int g = blockIdx.x, tid = threadIdx.x;
    const int s = seg[g], e = seg[g + 1];
    const int wid = tid >> 6, lane = tid & 63;
    __shared__ float red[4][8];
    __shared__ float smax[8];

    float mx[8];
    #pragma unroll
    for (int h = 0; h < 8; ++h) mx[h] = -1e30f;
    for (int i = s + tid; i < e; i += 256) {
        float4 l0 = *(const float4*)(logits + (size_t)i * 8);
        float4 l1 = *(const float4*)(logits + (size_t)i * 8 + 4);
        mx[0] = fmaxf(mx[0], l0.x); mx[1] = fmaxf(mx[1], l0.y);
        mx[2] = fmaxf(mx[2], l0.z); mx[3] = fmaxf(mx[3], l0.w);
        mx[4] = fmaxf(mx[4], l1.x); mx[5] = fmaxf(mx[5], l1.y);
        mx[6] = fmaxf(mx[6], l1.z); mx[7] = fmaxf(mx[7], l1.w);
    }
    #pragma unroll
    for (int m = 1; m < 64; m <<= 1)
        #pragma unroll
        for (int h = 0; h < 8; ++h) mx[h] = fmaxf(mx[h], __shfl_xor(mx[h], m));
    if (lane == 0) {
        #pragma unroll
        for (int h = 0; h < 8; ++h) red[wid][h] = mx[h];
    }
    __syncthreads();
    if (tid < 8)
        smax[tid] = fmaxf(fmaxf(red[0][tid], red[1][tid]),
                          fmaxf(red[2][tid], red[3][tid]));
    __syncthreads();
    float sm[8];
    #pragma unroll
    for (int h = 0; h < 8; ++h) sm[h] = smax[h];
    float su[8] = {0, 0, 0, 0, 0, 0, 0, 0};
    for (int i = s + tid; i < e; i += 256) {
        float4 l0 = *(const float4*)(logits + (size_t)i * 8);
        float4 l1 = *(const float4*)(logits + (size_t)i * 8 + 4);
        su[0] += __expf(l0.x - sm[0]); su[1] += __expf(l0.y - sm[1]);
        su[2] += __expf(l0.z - sm[2]); su[3] += __expf(l0.w - sm[3]);
        su[4] += __expf(l1.x - sm[4]); su[5] += __expf(l1.y - sm[5]);
        su[6] += __expf(l1.z - sm[6]); su[7] += __expf(l1.w - sm[7]);
    }
    #pragma unroll
    for (int m = 1; m < 64; m <<= 1)
        #pragma unroll
        for (int h = 0; h < 8; ++h) su[h] += __shfl_xor(su[h], m);
    __syncthreads();
    if (lane == 0) {
        #pragma unroll
        for (int h = 0; h < 8; ++h) red[wid][h] = su[h];
    }
    __syncthreads();
    if (tid < 8) {
        float d = red[0][tid] + red[1][tid] + red[2][tid] + red[3][tid];
        float sv = smax[tid];
        if (e == s) sv = 0.f;
        if (!(d > 0.f)) d = 1.f;
        smax8[g * 8 + tid] = sv;
        sinv8[g * 8 + tid] = 1.f / d;
    }
}

// ---------------- row-parallel weights + entropy + weighted pooling ----------------
// 1024 blocks x 256 contiguous rows; thread owns cols (2t, 2t+1); boundary flush via atomics.
__global__ __launch_bounds__(256) void k_wpool(
    const float* __restrict__ x, const float* __restrict__ logits,
    const int* __restrict__ batch, const float* __restrict__ smax8,
    const float* __restrict__ sinv8, float* __restrict__ graph_z,
    float* __restrict__ weights, float* __restrict__ ent)
{
    __shared__ float wsm[256][8];
    __shared__ int sbatch[256];
    __shared__ float red[4];

    const int tid = threadIdx.x;
    const int wid = tid >> 6, lane = tid & 63;
    const int base = blockIdx.x * 256;
    const int i = base + tid;

    const int g = batch[i];
    sbatch[tid] = g;
    float4 l0 = *(const float4*)(logits + (size_t)i * 8);
    float4 l1 = *(const float4*)(logits + (size_t)i * 8 + 4);
    float w[8];
    {
        const float* smp = smax8 + g * 8;
        const float* ivp = sinv8 + g * 8;
        w[0] = __expf(l0.x - smp[0]) * ivp[0];
        w[1] = __expf(l0.y - smp[1]) * ivp[1];
        w[2] = __expf(l0.z - smp[2]) * ivp[2];
        w[3] = __expf(l0.w - smp[3]) * ivp[3];
        w[4] = __expf(l1.x - smp[4]) * ivp[4];
        w[5] = __expf(l1.y - smp[5]) * ivp[5];
        w[6] = __expf(l1.z - smp[6]) * ivp[6];
        w[7] = __expf(l1.w - smp[7]) * ivp[7];
    }
    float entl = 0.f;
    #pragma unroll
    for (int h = 0; h < 8; ++h) {
        entl = fmaf(w[h], __logf(w[h] + 1e-8f), entl);
        wsm[tid][h] = w[h];
    }
    *(float4*)(weights + (size_t)i * 8)     = make_float4(w[0], w[1], w[2], w[3]);
    *(float4*)(weights + (size_t)i * 8 + 4) = make_float4(w[4], w[5], w[6], w[7]);

    #pragma unroll
    for (int m = 1; m < 64; m <<= 1) entl += __shfl_xor(entl, m);
    if (lane == 0) red[wid] = entl;
    __syncthreads();
    if (tid == 0)
        atomicAdd(ent, (red[0] + red[1] + red[2] + red[3]) * (-1.f / (GNUM * 8.f)));

    // weighted pooling over this 256-row chunk
    const int col = tid * 2;
    const int h = tid >> 5;                 // 64-col head blocks
    const float* xb = x + (size_t)base * HID + col;
    float ax = 0.f, ay = 0.f;
    int curg = sbatch[0];
    #pragma unroll 4
    for (int r2 = 0; r2 < 256; ++r2) {
        int g2 = sbatch[r2];
        if (g2 != curg) {   // wave-uniform, rare (~1/block)
            atomicAdd(&graph_z[(size_t)curg * HID + col], ax);
            atomicAdd(&graph_z[(size_t)curg * HID + col + 1], ay);
            ax = 0.f; ay = 0.f; curg = g2;
        }
        float wv = wsm[r2][h];
        float2 xv = *(const float2*)(xb + (size_t)r2 * HID);
        ax = fmaf(wv, xv.x, ax);
        ay = fmaf(wv, xv.y, ay);
    }
    atomicAdd(&graph_z[(size_t)curg * HID + col], ax);
    atomicAdd(&graph_z[(size_t)curg * HID + col + 1], ay);
}

extern "C" void kernel_launch(void* const* d_in, const int* in_sizes, int n_in,
                              void* d_out, int out_size, void* d_ws, size_t ws_size,
                              hipStream_t stream)
{
    const float* x     = (const float*)d_in[0];
    const int*   batch = (const int*)d_in[1];
    const float* gamma = (const float*)d_in[2];
    const float* beta  = (const float*)d_in[3];
    const float* W1    = (const float*)d_in[4];
    const float* b1    = (const float*)d_in[5];
    const float* W2    = (const float*)d_in[6];
    const float* b2    = (const float*)d_in[7];

    char* ws = (char*)d_ws;
    float*  logits = (float*)ws;                                    // 8 MB
    __bf16* w1t    = (__bf16*)(ws + (size_t)8 * 1024 * 1024);       // 256 KB
    int*    seg    = (int*)(ws + (size_t)8 * 1024 * 1024 + 512 * 1024);       // 4.1 KB
    float*  smax8  = (float*)(ws + (size_t)9 * 1024 * 1024);        // 32 KB
    float*  sinv8  = (float*)(ws + (size_t)9 * 1024 * 1024 + 64 * 1024);      // 32 KB

    float* out     = (float*)d_out;
    float* graph_z = out;                                           // [G,512]
    float* weights = out + (size_t)GNUM * HID;                      // [N,8]
    float* ent     = out + (size_t)GNUM * HID + (size_t)N_ROWS * HEADS;

    k_zero <<<512, 256, 0, stream>>>((float4*)graph_z, ent);
    k_prep <<<512, 256, 0, stream>>>(W1, w1t);
    k_seg  <<<5, 256, 0, stream>>>(batch, seg);
    k_gemm <<<N_ROWS / 64, 256, 0, stream>>>(x, gamma, beta, w1t, b1, W2, b2, logits);
    k_gmax <<<GNUM, 256, 0, stream>>>(logits, seg, smax8, sinv8);
    k_wpool<<<GNUM, 256, 0, stream>>>(x, logits, batch, smax8, sinv8, graph_z, weights, ent);
}